// Round 3
// baseline (267.942 us; speedup 1.0000x reference)
//
#include <hip/hip_runtime.h>
#include <hip/hip_bf16.h>
#include <stdint.h>

// KAN layer fused kernel, MI355X (gfx950) — V4: whole-W-in-LDS, 16 waves/block.
// out[M=65536, N=256] (fp32) = A[M, K=256] @ W^T, where
//   A[m,k] = c0[k]*B0(tanh(x[m,k])) + c1[k]*B1(tanh(x[m,k]))  (on the fly -> bf16)
//   W = outer_coeffs [N,K] fp32 -> bf16 (conv_w, SWIZZLED layout, into d_ws)
//
// Ladder so far:
//  - V1 58us: LDS B-staging, 2 barriers/K-step -> vmcnt(0) drains dominate.
//  - V2 87us: global per-lane B loads fragment (16x64B segments) + VGPR cap 96
//    sank loads next to MFMAs -> serialized.
//  - V3 44us: whole W (128KB bf16, pre-swizzled) staged to LDS once, zero-barrier
//    main loop, A in-register. But 512-thread block = 2 waves/SIMD (Occupancy 12%),
//    VALUBusy 36% -> ~64% of cycles are stalls. Bank-conflict counter 4/read is
//    structural b128 behavior (matches m134's linear-pattern ratio), not a lever.
//  - V4: SAME structure, 1024-thread block (16 waves x 16-row strips, no s-loop),
//    grid 256 -> 4 waves/SIMD. VGPR cap 128 (V3 used 112, fits).

typedef __attribute__((ext_vector_type(8))) short short8;   // 8 bf16 = 4 VGPR (MFMA A/B frag)
typedef __attribute__((ext_vector_type(4))) float f32x4;    // MFMA C/D frag

__device__ __forceinline__ uint16_t f2bf(float f) {
    union { float f; uint32_t u; } v; v.f = f;
    uint32_t r = v.u + 0x7FFFu + ((v.u >> 16) & 1u);  // RNE
    return (uint16_t)(r >> 16);
}

// Pack 2 floats -> 2 bf16 (RNE) in one v_cvt_pk_bf16_f32 (compiler-emitted)
__device__ __forceinline__ uint32_t pack_bf2(float lo, float hi) {
    __hip_bfloat162 h = __float22bfloat162_rn(make_float2(lo, hi));
    union { __hip_bfloat162 h; uint32_t u; } v; v.h = h;
    return v.u;
}

__device__ __forceinline__ float cube_relu(float v) {
    float m = fmaxf(v, 0.0f);
    return m * m * m;
}

__device__ __forceinline__ float inner_eval(float xx, float c0, float c1) {
    // tanh via exp: tanh(x) = 1 - 2/(e^{2x}+1); saturates correctly at +/-inf
    float e  = __expf(2.0f * xx);
    float t  = 1.0f - 2.0f * __builtin_amdgcn_rcpf(e + 1.0f);
    float u  = (t + 1.0f) * 3.5f;          // in [0,7]
    float w0 = cube_relu(u);
    float w1 = cube_relu(u - 1.0f);
    float w2 = cube_relu(u - 2.0f);
    float w3 = cube_relu(u - 3.0f);
    float w4 = cube_relu(u - 4.0f);
    float w5 = cube_relu(u - 5.0f);
    float B0 = w0 - 4.0f*w1 + 6.0f*w2 - 4.0f*w3 + w4;
    float B1 = w1 - 4.0f*w2 + 6.0f*w3 - 4.0f*w4 + w5;
    return (c0 * B0 + c1 * B1) * (1.0f / 6.0f);
}

__device__ __forceinline__ void load_lds16(const void* g, void* l) {
    __builtin_amdgcn_global_load_lds(
        (const __attribute__((address_space(1))) uint32_t*)g,
        (__attribute__((address_space(3))) uint32_t*)l, 16, 0, 0);
}

// W fp32 -> bf16 into the XOR-SWIZZLED layout kan_fused's ds_reads expect:
//   value W[row][col] lands at byte  row*512 + ((col*2) ^ ((row&7)<<4)).
// Thread i covers floats 4i..4i+3 = one 8-byte bf16 chunk (col*2 is 8-aligned;
// XOR touches bits 4..6 only, so the chunk stays 8-aligned and contiguous).
__global__ void conv_w(const float4* __restrict__ wf, char* __restrict__ o) {
    const int i = blockIdx.x * blockDim.x + threadIdx.x;  // 0..16383
    const float4 v = wf[i];
    uint2 r;
    r.x = (uint32_t)f2bf(v.x) | ((uint32_t)f2bf(v.y) << 16);
    r.y = (uint32_t)f2bf(v.z) | ((uint32_t)f2bf(v.w) << 16);
    const int row = i >> 6;           // 64 threads per 256-float row
    const int cb  = (i & 63) << 3;    // byte col within row, 8-aligned
    *(uint2*)(o + row * 512 + (cb ^ ((row & 7) << 4))) = r;
}

// Block: 1024 threads = 16 waves, grid 256 -> 1 block/CU, 4 waves/SIMD.
// Wave w owns rows [bid*256 + w*16, +16), all 256 output cols (16 n-tiles).
// MFMA operand mapping (verified V1-V3): lane=(mrow=lane&15, quad=lane>>4);
//   A frag: A[m=mrow][k=quad*8+j]; B frag: W[n=mrow][k=quad*8+j];
//   C/D: col=mrow, row=quad*4+r.
__global__ void __launch_bounds__(1024, 4) kan_fused(const float* __restrict__ x,
                                                     const float* __restrict__ ic,
                                                     const char* __restrict__ wb,
                                                     float* __restrict__ out)
{
    __shared__ __align__(16) char Wlds[131072];   // full W, bf16, swizzled
    __shared__ __align__(16) float2 C2[256];      // (c0,c1) per channel

    const int t    = threadIdx.x;
    const int lane = t & 63;
    const int w    = t >> 6;          // 0..15
    const int mrow = lane & 15;
    const int quad = lane >> 4;

    if (t < 256) C2[t] = make_float2(ic[t * 5 + 0], ic[t * 5 + 1]);

    const int mbase = blockIdx.x * 256 + w * 16;
    const float* xp = x + (size_t)(mbase + mrow) * 256 + quad * 8;

    // Early x prefetch for kk=0 (in flight during W staging)
    float4 xa = *(const float4*)(xp);
    float4 xb = *(const float4*)(xp + 4);

    // Stage all 128 KB of (pre-swizzled) W linearly: 8 issues x 16 waves x 1 KB.
    #pragma unroll
    for (int it = 0; it < 8; ++it) {
        const int base = ((it * 16 + w) << 10) + lane * 16;
        load_lds16(wb + base, Wlds + base);
    }
    __syncthreads();   // the ONLY barrier: drains vmcnt (W staged) + covers C2

    const int cbase = quad * 16;            // byte col base within a W row
    const int swz   = (mrow & 7) << 4;      // bank spread for b128 reads

    f32x4 acc[16];
    #pragma unroll
    for (int j = 0; j < 16; ++j) acc[j] = (f32x4){0.f, 0.f, 0.f, 0.f};

    #pragma unroll 1
    for (int kk = 0; kk < 8; ++kk) {
        // --- B frags from LDS (swizzled). Per lane: fixed col word, rows 8KB apart.
        const int cw = (kk * 64 + cbase) ^ swz;
        short8 b[16];
        #pragma unroll
        for (int j = 0; j < 16; ++j)
            b[j] = *(const short8*)(Wlds + (j * 16 + mrow) * 512 + cw);

        // --- next-iter x prefetch (hides HBM/L3 latency under spline VALU) ---
        float4 xa_n = xa, xb_n = xb;
        if (kk < 7) {
            xa_n = *(const float4*)(xp + kk * 32 + 32);
            xb_n = *(const float4*)(xp + kk * 32 + 36);
        }

        // --- coeffs for this lane's 8 channels (LDS broadcast) ---
        const int gk = kk * 32 + quad * 8;
        const float4 cA = *(const float4*)(&C2[gk + 0]);
        const float4 cB = *(const float4*)(&C2[gk + 2]);
        const float4 cC = *(const float4*)(&C2[gk + 4]);
        const float4 cD = *(const float4*)(&C2[gk + 6]);

        // --- spline VALU block ---
        float v0 = inner_eval(xa.x, cA.x, cA.y);
        float v1 = inner_eval(xa.y, cA.z, cA.w);
        float v2 = inner_eval(xa.z, cB.x, cB.y);
        float v3 = inner_eval(xa.w, cB.z, cB.w);
        float v4 = inner_eval(xb.x, cC.x, cC.y);
        float v5 = inner_eval(xb.y, cC.z, cC.w);
        float v6 = inner_eval(xb.z, cD.x, cD.y);
        float v7 = inner_eval(xb.w, cD.z, cD.w);

        union { short8 v; uint32_t u[4]; } af;
        af.u[0] = pack_bf2(v0, v1);
        af.u[1] = pack_bf2(v2, v3);
        af.u[2] = pack_bf2(v4, v5);
        af.u[3] = pack_bf2(v6, v7);

        // --- MFMA sweep over 16 n-tiles (16 independent acc chains) ---
        #pragma unroll
        for (int j = 0; j < 16; ++j)
            acc[j] = __builtin_amdgcn_mfma_f32_16x16x32_bf16(af.v, b[j], acc[j], 0, 0, 0);

        xa = xa_n; xb = xb_n;
    }

    // --- epilogue: fp32 stores; per inst: 4 quad-rows x 64B contiguous segments ---
    float* op = out + (size_t)(mbase + quad * 4) * 256 + mrow;
    #pragma unroll
    for (int j = 0; j < 16; ++j) {
        #pragma unroll
        for (int r = 0; r < 4; ++r)
            op[(size_t)r * 256 + j * 16] = acc[j][r];
    }
}

extern "C" void kernel_launch(void* const* d_in, const int* in_sizes, int n_in,
                              void* d_out, int out_size, void* d_ws, size_t ws_size,
                              hipStream_t stream) {
    const float* x  = (const float*)d_in[0];   // [16,4096,256] fp32
    const float* ic = (const float*)d_in[1];   // [256,5] fp32
    const float* oc = (const float*)d_in[2];   // [256,256] fp32
    char* wb = (char*)d_ws;                    // 128 KB bf16 swizzled copy of W

    conv_w<<<64, 256, 0, stream>>>((const float4*)oc, wb);
    kan_fused<<<256, 1024, 0, stream>>>(x, ic, wb, (float*)d_out);
}

// Round 4
// 208.618 us; speedup vs baseline: 1.2844x; 1.2844x over previous
//
#include <hip/hip_runtime.h>
#include <hip/hip_bf16.h>
#include <stdint.h>

// KAN layer fused kernel, MI355X (gfx950) — V5: phase-split strips, whole-W LDS.
// out[M=65536, N=256] (fp32) = A[M, K=256] @ W^T, where
//   A[m,k] = c0[k]*B0(tanh(x[m,k])) + c1[k]*B1(tanh(x[m,k]))  (on the fly -> bf16)
//   W = outer_coeffs [N,K] fp32 -> bf16 (conv_w, SWIZZLED layout, into d_ws)
//   conv_w also packs C2g[256] = (ic[k][0], ic[k][1]) at d_ws+131072.
//
// Ladder: V1 58us (per-K barriers) -> V2 87us (global B, VGPR-96 serialization)
//   -> V3 44us (whole-W LDS, zero-barrier loop, 2 waves/SIMD, VGPR 112)
//   -> V4 181us (1024-thr: compiler targeted 64 VGPR and SPILLED acc/b; 560MB scratch).
// V5 keeps V3's 512-thr/cap-256 geometry and removes V3's per-K-step stalls:
//  - per strip: load ALL x (16 float4) -> pure-VALU spline for all 8 K-steps ->
//    uninterrupted 128 ds_read + 128 MFMA sweep -> stores.
//  - strip 1's x issued BEFORE strip 0's MFMA sweep (~10K cyc cover vs 900 cyc HBM).
//  - coeffs from a global packed table, copied to LDS by EVERY wave (same-value
//    benign race -> no barrier); the single __syncthreads (W DMA) sits after the
//    strip-0 spline, fully hidden.
//  - vmcnt is in-order: x and coeff loads are issued BEFORE the W DMA so their
//    waits don't drain it.

typedef __attribute__((ext_vector_type(8))) short short8;   // 8 bf16 = 4 VGPR (MFMA A/B frag)
typedef __attribute__((ext_vector_type(4))) float f32x4;    // MFMA C/D frag

__device__ __forceinline__ uint16_t f2bf(float f) {
    union { float f; uint32_t u; } v; v.f = f;
    uint32_t r = v.u + 0x7FFFu + ((v.u >> 16) & 1u);  // RNE
    return (uint16_t)(r >> 16);
}

// Pack 2 floats -> 2 bf16 (RNE) in one v_cvt_pk_bf16_f32 (compiler-emitted)
__device__ __forceinline__ uint32_t pack_bf2(float lo, float hi) {
    __hip_bfloat162 h = __float22bfloat162_rn(make_float2(lo, hi));
    union { __hip_bfloat162 h; uint32_t u; } v; v.h = h;
    return v.u;
}

__device__ __forceinline__ float cube_relu(float v) {
    float m = fmaxf(v, 0.0f);
    return m * m * m;
}

__device__ __forceinline__ float inner_eval(float xx, float c0, float c1) {
    // tanh via exp: tanh(x) = 1 - 2/(e^{2x}+1); saturates correctly at +/-inf
    float e  = __expf(2.0f * xx);
    float t  = 1.0f - 2.0f * __builtin_amdgcn_rcpf(e + 1.0f);
    float u  = (t + 1.0f) * 3.5f;          // in [0,7]
    float w0 = cube_relu(u);
    float w1 = cube_relu(u - 1.0f);
    float w2 = cube_relu(u - 2.0f);
    float w3 = cube_relu(u - 3.0f);
    float w4 = cube_relu(u - 4.0f);
    float w5 = cube_relu(u - 5.0f);
    float B0 = w0 - 4.0f*w1 + 6.0f*w2 - 4.0f*w3 + w4;
    float B1 = w1 - 4.0f*w2 + 6.0f*w3 - 4.0f*w4 + w5;
    return (c0 * B0 + c1 * B1) * (1.0f / 6.0f);
}

__device__ __forceinline__ void load_lds16(const void* g, void* l) {
    __builtin_amdgcn_global_load_lds(
        (const __attribute__((address_space(1))) uint32_t*)g,
        (__attribute__((address_space(3))) uint32_t*)l, 16, 0, 0);
}

// W fp32 -> bf16 into the XOR-SWIZZLED layout kan_fused's ds_reads expect:
//   value W[row][col] lands at byte  row*512 + ((col*2) ^ ((row&7)<<4)).
// Also packs the (c0,c1) coeff table at offset 131072 (2 KB).
__global__ void conv_w(const float* __restrict__ ic, const float4* __restrict__ wf,
                       char* __restrict__ o) {
    const int i = blockIdx.x * blockDim.x + threadIdx.x;  // 0..16383
    const float4 v = wf[i];
    uint2 r;
    r.x = (uint32_t)f2bf(v.x) | ((uint32_t)f2bf(v.y) << 16);
    r.y = (uint32_t)f2bf(v.z) | ((uint32_t)f2bf(v.w) << 16);
    const int row = i >> 6;           // 64 threads per 256-float row
    const int cb  = (i & 63) << 3;    // byte col within row, 8-aligned
    *(uint2*)(o + row * 512 + (cb ^ ((row & 7) << 4))) = r;
    if (i < 256)
        *(float2*)(o + 131072 + i * 8) = make_float2(ic[i * 5 + 0], ic[i * 5 + 1]);
}

// A-fragment for one K-step: 8 inner_evals + pack to short8.
__device__ __forceinline__ short8 spline8(float4 xa, float4 xb, const float2* C2, int gk) {
    const float4 cA = *(const float4*)(&C2[gk + 0]);   // c0,c1 of ch gk, gk+1
    const float4 cB = *(const float4*)(&C2[gk + 2]);
    const float4 cC = *(const float4*)(&C2[gk + 4]);
    const float4 cD = *(const float4*)(&C2[gk + 6]);
    float v0 = inner_eval(xa.x, cA.x, cA.y);
    float v1 = inner_eval(xa.y, cA.z, cA.w);
    float v2 = inner_eval(xa.z, cB.x, cB.y);
    float v3 = inner_eval(xa.w, cB.z, cB.w);
    float v4 = inner_eval(xb.x, cC.x, cC.y);
    float v5 = inner_eval(xb.y, cC.z, cC.w);
    float v6 = inner_eval(xb.z, cD.x, cD.y);
    float v7 = inner_eval(xb.w, cD.z, cD.w);
    union { short8 v; uint32_t u[4]; } af;
    af.u[0] = pack_bf2(v0, v1);
    af.u[1] = pack_bf2(v2, v3);
    af.u[2] = pack_bf2(v4, v5);
    af.u[3] = pack_bf2(v6, v7);
    return af.v;
}

// Full-K MFMA sweep (128 ds_read_b128 + 128 MFMA, b in groups of 8) + stores.
__device__ __forceinline__ void mfma_store(const short8* af, const char* Wlds,
                                           float* __restrict__ out, int mbase,
                                           int mrow, int quad, int swz) {
    f32x4 acc[16];
    #pragma unroll
    for (int j = 0; j < 16; ++j) acc[j] = (f32x4){0.f, 0.f, 0.f, 0.f};

    #pragma unroll
    for (int kk = 0; kk < 8; ++kk) {
        const int cw = (kk * 64 + quad * 16) ^ swz;
        short8 bg[8];
        #pragma unroll
        for (int j = 0; j < 8; ++j)
            bg[j] = *(const short8*)(Wlds + ((j * 16 + mrow) << 9) + cw);
        #pragma unroll
        for (int j = 0; j < 8; ++j)
            acc[j] = __builtin_amdgcn_mfma_f32_16x16x32_bf16(af[kk], bg[j], acc[j], 0, 0, 0);
        #pragma unroll
        for (int j = 0; j < 8; ++j)
            bg[j] = *(const short8*)(Wlds + (((j + 8) * 16 + mrow) << 9) + cw);
        #pragma unroll
        for (int j = 0; j < 8; ++j)
            acc[j + 8] = __builtin_amdgcn_mfma_f32_16x16x32_bf16(af[kk], bg[j], acc[j + 8], 0, 0, 0);
    }

    // epilogue: per inst 4 quad-rows x 64B contiguous segments
    float* op = out + (size_t)(mbase + quad * 4) * 256 + mrow;
    #pragma unroll
    for (int j = 0; j < 16; ++j) {
        #pragma unroll
        for (int r = 0; r < 4; ++r)
            op[(size_t)r * 256 + j * 16] = acc[j][r];
    }
}

// Block: 512 threads = 8 waves, grid 256 -> 1 block/CU (LDS-limited, 2 waves/SIMD).
// Wave w handles strips (s*8+w)*16 rows, s=0..1; all 256 output cols (16 n-tiles).
// Lane mapping (verified V1-V4): mrow=lane&15, quad=lane>>4;
//   A frag: A[m=mrow][k=quad*8+i]; B frag: W[n=mrow][k=quad*8+i]; C/D: col=mrow, row=quad*4+r.
__global__ void __launch_bounds__(512, 2) kan_fused(const float* __restrict__ x,
                                                    const char* __restrict__ wb,
                                                    float* __restrict__ out)
{
    __shared__ __align__(16) char smem[133120];
    char*   Wlds = smem;                       // [256 rows][512 B], swizzled
    float2* C2   = (float2*)(smem + 131072);   // (c0,c1) per channel

    const int t    = threadIdx.x;
    const int lane = t & 63;
    const int w    = t >> 6;
    const int mrow = lane & 15;
    const int quad = lane >> 4;
    const int swz  = (mrow & 7) << 4;

    const int mb0 = blockIdx.x * 256 + w * 16;   // strip 0 rows
    const int mb1 = mb0 + 128;                   // strip 1 rows

    const float* xr0 = x + (size_t)(mb0 + mrow) * 256 + quad * 8;
    const float* xr1 = x + (size_t)(mb1 + mrow) * 256 + quad * 8;

    // (1) strip-0 x: 16 float4, issued FIRST (in-order vmcnt: their waits won't
    //     drain the W DMA issued below)
    float4 xv[16];
    #pragma unroll
    for (int kk = 0; kk < 8; ++kk) {
        xv[2 * kk]     = *(const float4*)(xr0 + kk * 32);
        xv[2 * kk + 1] = *(const float4*)(xr0 + kk * 32 + 4);
    }

    // (2) coeff table from global (packed by conv_w; L2-hot)
    const float4* c2g = (const float4*)(wb + 131072);
    const float4 cg0 = c2g[lane * 2];
    const float4 cg1 = c2g[lane * 2 + 1];

    // (3) W DMA: 128 KB linear, 16 rounds x 8 waves x 1 KB (completes under spline)
    #pragma unroll
    for (int it = 0; it < 16; ++it) {
        const int base = ((it * 8 + w) << 10) + lane * 16;
        load_lds16(wb + base, Wlds + base);
    }

    // (4) every wave writes the whole 2 KB C2 table (identical values: benign race;
    //     own-wave lgkm ordering makes it readable with NO barrier)
    *(float4*)((char*)C2 + lane * 32)      = cg0;
    *(float4*)((char*)C2 + lane * 32 + 16) = cg1;

    // (5) spline strip 0: pure VALU, all 8 A-fragments
    short8 af[8];
    #pragma unroll
    for (int kk = 0; kk < 8; ++kk)
        af[kk] = spline8(xv[2 * kk], xv[2 * kk + 1], C2, kk * 32 + quad * 8);

    __syncthreads();   // the ONLY barrier: W staged (DMA hidden under the spline)

    // (6) strip-1 x prefetch: in flight under strip-0's MFMA sweep (~10K cyc cover)
    #pragma unroll
    for (int kk = 0; kk < 8; ++kk) {
        xv[2 * kk]     = *(const float4*)(xr1 + kk * 32);
        xv[2 * kk + 1] = *(const float4*)(xr1 + kk * 32 + 4);
    }

    // (7) strip 0: uninterrupted 128 ds_read + 128 MFMA, then stores
    mfma_store(af, Wlds, out, mb0, mrow, quad, swz);

    // (8) spline strip 1 (x arrived during MFMA-0)
    #pragma unroll
    for (int kk = 0; kk < 8; ++kk)
        af[kk] = spline8(xv[2 * kk], xv[2 * kk + 1], C2, kk * 32 + quad * 8);

    // (9) strip 1: MFMA + stores
    mfma_store(af, Wlds, out, mb1, mrow, quad, swz);
}

extern "C" void kernel_launch(void* const* d_in, const int* in_sizes, int n_in,
                              void* d_out, int out_size, void* d_ws, size_t ws_size,
                              hipStream_t stream) {
    const float* x  = (const float*)d_in[0];   // [16,4096,256] fp32
    const float* ic = (const float*)d_in[1];   // [256,5] fp32
    const float* oc = (const float*)d_in[2];   // [256,256] fp32
    char* wb = (char*)d_ws;                    // 128 KB swizzled W + 2 KB coeff table

    conv_w<<<64, 256, 0, stream>>>(ic, (const float4*)oc, wb);
    kan_fused<<<256, 512, 0, stream>>>(x, wb, (float*)d_out);
}